// Round 16
// baseline (243.957 us; speedup 1.0000x reference)
//
#include <hip/hip_runtime.h>

#define B_ 8
#define N_ 1024
#define DIM_ 512
#define H_ 8
#define DH_ 64
#define SCALE_ 0.125f
#define EPS_ 1e-6f
#define EPSN_ (1e-6f / 1024.0f)
#define C2_ (0.125f * 1.4426950408889634f)   // SCALE * log2(e)

typedef unsigned short u16;
typedef unsigned int u32;
typedef __attribute__((ext_vector_type(8))) short short8;
typedef __attribute__((ext_vector_type(8))) unsigned short ushort8;
typedef __attribute__((ext_vector_type(4))) unsigned short ushort4v;
typedef __attribute__((ext_vector_type(2))) unsigned int uint2v;
typedef __attribute__((ext_vector_type(4))) float f32x4;

__device__ __forceinline__ u16 f2b(float f) {
    union { float f; unsigned u; } v; v.f = f;
    unsigned r = v.u + 0x7fffu + ((v.u >> 16) & 1u);
    return (u16)(r >> 16);
}

__device__ __forceinline__ u32 cvtpk(float lo, float hi) {
    u32 r;
    asm("v_cvt_pk_bf16_f32 %0, %1, %2" : "=v"(r) : "v"(lo), "v"(hi));
    return r;
}

__device__ __forceinline__ f32x4 mfma16(short8 a, short8 b, f32x4 c) {
    return __builtin_amdgcn_mfma_f32_16x16x32_bf16(a, b, c, 0, 0, 0);
}

__device__ __forceinline__ void gload16(const u16* g, u16* l) {
    __builtin_amdgcn_global_load_lds(
        (const __attribute__((address_space(1))) void*)g,
        (__attribute__((address_space(3))) void*)l, 16, 0, 0);
}

// ---- shared pipeline macros ----
#define WAITB(n) do {                                         \
    asm volatile("s_waitcnt vmcnt(" #n ")" ::: "memory");     \
    __builtin_amdgcn_s_barrier();                             \
    asm volatile("" ::: "memory");                            \
} while (0)

#define ENDB do {                                             \
    asm volatile("" ::: "memory");                            \
    __builtin_amdgcn_s_barrier();                             \
} while (0)

// fused prep: LDS-tiled transposes (both sides coalesced) + x->bf16 cvt.
__global__ __launch_bounds__(256) void prep(
    const float* __restrict__ W_qkv, const float* __restrict__ W_out,
    const float* __restrict__ x,
    u16* __restrict__ wqkvT, u16* __restrict__ woutT, u16* __restrict__ Xb) {
    __shared__ float tl[64][65];
    const int t = threadIdx.x;
    const int blk = blockIdx.x;
    if (blk < 256) {
        const float* in; u16* out; int R, C, bx, by;
        if (blk < 192) { in = W_qkv; out = wqkvT; R = 512; C = 1536; bx = blk % 24; by = blk / 24; }
        else           { in = W_out; out = woutT; R = 512; C = 512;  bx = (blk - 192) & 7; by = (blk - 192) >> 3; }
        const int r0 = by * 64, c0 = bx * 64;
        const int rsub = t >> 6, col = t & 63;
#pragma unroll
        for (int k = 0; k < 16; ++k) {
            int row = k * 4 + rsub;
            tl[row][col] = in[(size_t)(r0 + row) * C + c0 + col];
        }
        __syncthreads();
#pragma unroll
        for (int k = 0; k < 16; ++k) {
            int orow = k * 4 + rsub;
            int ocol = col;
            out[(size_t)(c0 + orow) * R + r0 + ocol] = f2b(tl[ocol][orow]);
        }
    } else {
        int i2 = (blk - 256) * 2048 + t * 8;
        float4 f0 = *(const float4*)(x + i2);
        float4 f1 = *(const float4*)(x + i2 + 4);
        ushort8 o;
        o[0]=f2b(f0.x); o[1]=f2b(f0.y); o[2]=f2b(f0.z); o[3]=f2b(f0.w);
        o[4]=f2b(f1.x); o[5]=f2b(f1.y); o[6]=f2b(f1.z); o[7]=f2b(f1.w);
        *(ushort8*)(Xb + i2) = o;
    }
}

// ---- 128x128 tile, BK=64 GEMM pipeline (shared by gemm_qkv / gemm_out) ----
#define GSTAGE(buf, k0) do {                                                  \
    _Pragma("unroll")                                                         \
    for (int call = 0; call < 4; ++call) {                                    \
        const int rr2 = call * 32 + srow;                                     \
        gload16(Xb + (size_t)(rowbase + rr2) * DIM_ + (k0) + sch * 8,         \
                Alf + (buf) * 8192 + call * 2048 + t * 8);                    \
        gload16(BT + (size_t)(colbase + rr2) * DIM_ + (k0) + sch * 8,         \
                Blf + (buf) * 8192 + call * 2048 + t * 8);                    \
    }                                                                         \
} while (0)

#define QCOMP(bsel) do {                                                      \
    _Pragma("unroll")                                                         \
    for (int kk = 0; kk < 64; kk += 32) {                                     \
        short8 af[4], bf[4];                                                  \
        _Pragma("unroll")                                                     \
        for (int m = 0; m < 4; ++m) {                                         \
            const int ar = wr * 64 + m * 16 + lr;                             \
            const int slot = ((kk >> 3) + lg) ^ (lr & 7);                     \
            af[m] = *(const short8*)&Alf[(bsel) * 8192 + ar * 64 + slot * 8]; \
        }                                                                     \
        _Pragma("unroll")                                                     \
        for (int n = 0; n < 4; ++n) {                                         \
            const int br = wc * 64 + n * 16 + lr;                             \
            const int slot = ((kk >> 3) + lg) ^ (lr & 7);                     \
            bf[n] = *(const short8*)&Blf[(bsel) * 8192 + br * 64 + slot * 8]; \
        }                                                                     \
        _Pragma("unroll")                                                     \
        for (int m = 0; m < 4; ++m)                                           \
            _Pragma("unroll")                                                 \
            for (int n = 0; n < 4; ++n)                                       \
                acc[m][n] = mfma16(af[m], bf[n], acc[m][n]);                  \
    }                                                                         \
} while (0)

#define GEMM_PIPE do {                                                        \
    GSTAGE(0, 0);                                                             \
    GSTAGE(1, 64);  WAITB(8); QCOMP(0); ENDB;                                 \
    GSTAGE(0, 128); WAITB(8); QCOMP(1); ENDB;                                 \
    GSTAGE(1, 192); WAITB(8); QCOMP(0); ENDB;                                 \
    GSTAGE(0, 256); WAITB(8); QCOMP(1); ENDB;                                 \
    GSTAGE(1, 320); WAITB(8); QCOMP(0); ENDB;                                 \
    GSTAGE(0, 384); WAITB(8); QCOMP(1); ENDB;                                 \
    GSTAGE(1, 448); WAITB(8); QCOMP(0); ENDB;                                 \
    WAITB(0); QCOMP(1);                                                       \
} while (0)

__global__ __launch_bounds__(256, 2) void gemm_qkv(
    const u16* __restrict__ Xb, const u16* __restrict__ BT,
    u16* __restrict__ Qw, u16* __restrict__ Kw, u16* __restrict__ Vt) {
    __shared__ u16 Al[2 * 8192];
    __shared__ u16 Bl[2 * 8192];
    u16* Alf = &Al[0];
    u16* Blf = &Bl[0];
    const int t = threadIdx.x;
    const int w = t >> 6, l = t & 63, lg = l >> 4, lr = l & 15;
    const int wr = w >> 1, wc = w & 1;
    const int rowbase = blockIdx.y * 128, colbase = blockIdx.x * 128;
    const int srow = t >> 3;
    const int sch = (t & 7) ^ (srow & 7);

    f32x4 acc[4][4];
#pragma unroll
    for (int m = 0; m < 4; m++)
#pragma unroll
        for (int n = 0; n < 4; n++) acc[m][n] = (f32x4){0.f, 0.f, 0.f, 0.f};

    GEMM_PIPE;

#pragma unroll
    for (int m = 0; m < 4; m++) {
#pragma unroll
        for (int n = 0; n < 4; n++) {
#pragma unroll
            for (int j = 0; j < 4; j++) {
                int token = rowbase + wr * 64 + m * 16 + 4 * lg + j;
                int b = token >> 10, nn = token & (N_ - 1);
                int c = colbase + wc * 64 + n * 16 + lr;
                u16 v = f2b(acc[m][n][j]);
                if (c < 512) {
                    int h = c >> 6, d = c & 63;
                    Qw[((size_t)(b * H_ + h) * N_ + nn) * DH_ + d] = v;
                } else if (c < 1024) {
                    int c2 = c - 512, h = c2 >> 6, d = c2 & 63;
                    Kw[((size_t)(b * H_ + h) * N_ + nn) * DH_ + d] = v;
                } else {
                    int c2 = c - 1024, h = c2 >> 6, d = c2 & 63;
                    Vt[((size_t)(b * H_ + h) * DH_ + d) * N_ + nn] = v;
                }
            }
        }
    }
}

// A [8192][512] @ BT [512][512] (+bias) -> out f32, same pipeline
__global__ __launch_bounds__(256, 2) void gemm_out(
    const u16* __restrict__ Xb, const u16* __restrict__ BT,
    const float* __restrict__ bout, float* __restrict__ out) {
    __shared__ u16 Al[2 * 8192];
    __shared__ u16 Bl[2 * 8192];
    u16* Alf = &Al[0];
    u16* Blf = &Bl[0];
    const int t = threadIdx.x;
    const int w = t >> 6, l = t & 63, lg = l >> 4, lr = l & 15;
    const int wr = w >> 1, wc = w & 1;
    const int rowbase = blockIdx.y * 128, colbase = blockIdx.x * 128;
    const int srow = t >> 3;
    const int sch = (t & 7) ^ (srow & 7);

    f32x4 acc[4][4];
#pragma unroll
    for (int m = 0; m < 4; m++)
#pragma unroll
        for (int n = 0; n < 4; n++) acc[m][n] = (f32x4){0.f, 0.f, 0.f, 0.f};

    GEMM_PIPE;

#pragma unroll
    for (int n = 0; n < 4; n++) {
        const int cc = colbase + wc * 64 + n * 16 + lr;
        const float bv = bout[cc];
#pragma unroll
        for (int m = 0; m < 4; m++) {
#pragma unroll
            for (int j = 0; j < 4; j++) {
                int token = rowbase + wr * 64 + m * 16 + 4 * lg + j;
                out[(size_t)token * DIM_ + cc] = acc[m][n][j] + bv;
            }
        }
    }
}

// ---- attn macros (R14 proven schedule; mask table as u16 0/1) ----
// pass 1: 128-col K tiles into unified 2x16KB dbuf (SH)
#define STAGE_K2(c2) do {                                                     \
    gload16(Kb + ((size_t)((c2) * 128 + srow_)) * 64 + sch_ * 8,              \
            SH + ((c2) & 1) * 8192 + t * 8);                                  \
    gload16(Kb + ((size_t)((c2) * 128 + 64 + srow_)) * 64 + sch_ * 8,         \
            SH + ((c2) & 1) * 8192 + 4096 + t * 8);                           \
} while (0)

#define SUM128(c2) do {                                                       \
    _Pragma("unroll")                                                         \
    for (int sub = 0; sub < 8; ++sub) {                                       \
        const u16* kb = SH + ((c2) & 1) * 8192 + (sub >> 2) * 4096            \
                        + ((sub & 3) * 16 + lr) * 64;                         \
        short8 kf0 = *(const short8*)(kb + kswz);                             \
        short8 kf1 = *(const short8*)(kb + (kswz ^ 32));                      \
        f32x4 d = {0.f, 0.f, 0.f, 0.f};                                       \
        d = mfma16(kf0, qf0, d);                                              \
        d = mfma16(kf1, qf1, d);                                              \
        const int kb2 = (c2) * 128 + sub * 16 + 4 * lg;                       \
        ushort4v mv = *(const ushort4v*)&maskL[kb2];                          \
        _Pragma("unroll")                                                     \
        for (int j = 0; j < 4; ++j) {                                         \
            float E = __builtin_amdgcn_exp2f(d[j] * C2_);                     \
            float mm = (mv[j] || (kb2 + j == q)) ? 1.f : 0.f;                 \
            sp += E;                                                          \
            so = fmaf(E, mm, so);                                             \
        }                                                                     \
    }                                                                         \
} while (0)

// pass 2 (R13/R14 proven): 64-col phases; K in SH[0..8191], V in SH[8192..]
#define STAGE_K(c) gload16(Kb + ((size_t)((c) * 64 + srow_)) * 64 + sch_ * 8, \
                           SH + ((c) & 1) * 4096 + t * 8)
#define STAGE_V(c) gload16(Vb + (size_t)srow_ * N_ + (c) * 64 + sch_ * 8,     \
                           SH + 8192 + ((c) & 1) * 4096 + t * 8)

#define QKTILE(c) do {                                                        \
    _Pragma("unroll")                                                         \
    for (int sub = 0; sub < 4; ++sub) {                                       \
        const u16* kb = SH + ((c) & 1) * 4096 + (sub * 16 + lr) * 64;         \
        short8 kf0 = *(const short8*)(kb + kswz);                             \
        short8 kf1 = *(const short8*)(kb + (kswz ^ 32));                      \
        f32x4 d = {0.f, 0.f, 0.f, 0.f};                                       \
        d = mfma16(kf0, qf0, d);                                              \
        d = mfma16(kf1, qf1, d);                                              \
        const int kb2 = (c) * 64 + sub * 16 + 4 * lg;                         \
        ushort4v mv = *(const ushort4v*)&maskL[kb2];                          \
        f32x4 ov; float p[4];                                                 \
        _Pragma("unroll")                                                     \
        for (int j = 0; j < 4; ++j) {                                         \
            float E = __builtin_amdgcn_exp2f(d[j] * C2_);                     \
            ov[j] = E * rip;                                                  \
            float mm = (mv[j] || (kb2 + j == q)) ? 1.f : 0.f;                 \
            p[j] = fmaf(E * mm, rpo, eb);                                     \
        }                                                                     \
        uint2v wv2;                                                           \
        wv2[0] = cvtpk(p[0], p[1]);                                           \
        wv2[1] = cvtpk(p[2], p[3]);                                           \
        *(f32x4*)(srow + (c) * 64 + sub * 16 + 4 * lg) = ov;                  \
        *(uint2v*)&wl[wid][lr][sub * 16 + 4 * lg] = wv2;                      \
    }                                                                         \
} while (0)

#define PVTILE(c) do {                                                        \
    __builtin_amdgcn_s_setprio(1);                                            \
    _Pragma("unroll")                                                         \
    for (int ks = 0; ks < 64; ks += 32) {                                     \
        short8 af = *(const short8*)&wl[wid][lr][ks + 8 * lg];                \
        _Pragma("unroll")                                                     \
        for (int dt = 0; dt < 4; ++dt) {                                      \
            const u16* vb = SH + 8192 + ((c) & 1) * 4096 + (dt * 16 + lr) * 64; \
            short8 vf = *(const short8*)(vb + (ks ? (kswz ^ 32) : kswz));     \
            apv[dt] = mfma16(af, vf, apv[dt]);                                \
        }                                                                     \
    }                                                                         \
    __builtin_amdgcn_s_setprio(0);                                            \
} while (0)

// 512 blocks x 8 waves (128 q-rows/block), single tranche, XCD-swizzled.
// LB(512,3): VGPR cap ~85 -> target 3 blocks/CU (the (512,4)=cap64 variant
// spilled; (512,2)=cap128 was clean at 2 blocks/CU). LDS trimmed to 52KB
// (mask u16) so 3 blocks fit in 160KB.
__global__ __launch_bounds__(512, 3) void attn_kernel(
    const u16* __restrict__ Qw, const u16* __restrict__ Kw, const u16* __restrict__ Vt,
    const float* __restrict__ policy, u16* __restrict__ outpre, float* __restrict__ softout) {
    __shared__ u16 SH[16384];      // p1: 2x16KB K128 dbuf; p2: K dbuf | V dbuf
    __shared__ u16 wl[8][16][72];
    __shared__ u16 maskL[N_];

    const int t = threadIdx.x;
    const int wid = t >> 6, l = t & 63, lg = (l >> 4), lr = l & 15;
    const int srow_ = t >> 3, sch_ = (t & 7) ^ ((t >> 3) & 7);
    const int kswz = (lg ^ (lr & 7)) * 8;

    const int bid = blockIdx.x;              // 512 = 8 xcd * 64
    const int xcd = bid & 7, rr = bid >> 3;
    const int g = rr >> 3, rt = rr & 7;
    const int bh = g * 8 + xcd;
    const int b = bh >> 3, h = bh & 7;
    const int n0 = rt * 128 + wid * 16;
    const int q = n0 + lr;

    const u16* Qb = Qw + ((size_t)bh * N_ + n0) * DH_;
    const u16* Kb = Kw + (size_t)bh * N_ * DH_;
    const u16* Vb = Vt + (size_t)bh * DH_ * N_;
    const float* pol = policy + b * N_;

    short8 qf0 = *(const short8*)(Qb + lr * DH_ + 8 * lg);
    short8 qf1 = *(const short8*)(Qb + lr * DH_ + 32 + 8 * lg);

    {
        float2 pv = *(const float2*)(pol + t * 2);
        maskL[t * 2 + 0] = pv.x > 0.5f ? 1 : 0;
        maskL[t * 2 + 1] = pv.y > 0.5f ? 1 : 0;
    }
    __syncthreads();

    // ---- pass 1: row sums, 128-col staged K phases ----
    float sp = 0.f, so = 0.f;
    STAGE_K2(0);
#define ITER1(c2, n) do { STAGE_K2(n); WAITB(2); SUM128(c2); ENDB; } while (0)
    ITER1(0, 1); ITER1(1, 2); ITER1(2, 3); ITER1(3, 4);
    ITER1(4, 5); ITER1(5, 6); ITER1(6, 7);
    WAITB(0); SUM128(7); ENDB;

    sp += __shfl_xor(sp, 16); sp += __shfl_xor(sp, 32);
    so += __shfl_xor(so, 16); so += __shfl_xor(so, 32);
    const float rip = 1.f / sp;
    const float rpo = 1.f / (so + EPS_);
    const float eb = EPSN_ * rpo;

    // ---- pass 2: softmax stream + PV, staged K+V (R13 schedule) ----
    f32x4 apv[4];
#pragma unroll
    for (int i = 0; i < 4; i++) apv[i] = (f32x4){0, 0, 0, 0};
    float* srow = softout + ((size_t)bh * N_ + q) * N_;

    STAGE_K(0); STAGE_V(0);
    // c=0: outstanding S0(2)+S1(2) -> wait S0 => vmcnt(2)
    STAGE_K(1); STAGE_V(1); WAITB(2); QKTILE(0); PVTILE(0); ENDB;
    // c=1..14: younger-than-S(c) = stores(4)+S(c+1)(2) => vmcnt(6)
#define ITER2(c, n) do { STAGE_K(n); STAGE_V(n); WAITB(6); QKTILE(c); PVTILE(c); ENDB; } while (0)
    ITER2(1, 2);  ITER2(2, 3);  ITER2(3, 4);  ITER2(4, 5);
    ITER2(5, 6);  ITER2(6, 7);  ITER2(7, 8);  ITER2(8, 9);
    ITER2(9, 10); ITER2(10, 11); ITER2(11, 12); ITER2(12, 13);
    ITER2(13, 14); ITER2(14, 15);
    // c=15: younger-than-S15 = stores_c14(4) => vmcnt(4)
    WAITB(4); QKTILE(15); PVTILE(15);

#pragma unroll
    for (int dt = 0; dt < 4; dt++) {
#pragma unroll
        for (int j = 0; j < 4; j++) {
            outpre[(size_t)(b * N_ + n0 + 4 * lg + j) * DIM_ + h * DH_ + dt * 16 + lr]
                = f2b(apv[dt][j]);
        }
    }
}

extern "C" void kernel_launch(void* const* d_in, const int* in_sizes, int n_in,
                              void* d_out, int out_size, void* d_ws, size_t ws_size,
                              hipStream_t stream) {
    const float* x      = (const float*)d_in[0];
    const float* policy = (const float*)d_in[1];
    const float* W_qkv  = (const float*)d_in[2];
    const float* W_out  = (const float*)d_in[3];
    const float* b_out  = (const float*)d_in[4];
    float* out = (float*)d_out;
    float* softout = out + (size_t)B_ * N_ * DIM_;

    // ws: wqkvT 1.5M | woutT .5M | Xb 8M | Qw 8M | Kw 8M | Vt 8M | pre 8M
    char* ws = (char*)d_ws;
    u16* wqkvT = (u16*)ws;
    u16* woutT = (u16*)(ws + 1572864);
    u16* Xb    = (u16*)(ws + 2097152);
    u16* Qw    = (u16*)(ws + 10485760);
    u16* Kw    = (u16*)(ws + 18874368);
    u16* Vt    = (u16*)(ws + 27262976);
    u16* pre   = (u16*)(ws + 35651584);

    prep<<<2304, 256, 0, stream>>>(W_qkv, W_out, x, wqkvT, woutT, Xb);
    gemm_qkv<<<dim3(12, 64), 256, 0, stream>>>(Xb, wqkvT, Qw, Kw, Vt);
    attn_kernel<<<512, 512, 0, stream>>>(Qw, Kw, Vt, policy, pre, softout);
    gemm_out<<<dim3(4, 64), 256, 0, stream>>>(pre, woutT, b_out, out);
}

// Round 17
// 167.747 us; speedup vs baseline: 1.4543x; 1.4543x over previous
//
#include <hip/hip_runtime.h>

#define B_ 8
#define N_ 1024
#define DIM_ 512
#define H_ 8
#define DH_ 64
#define SCALE_ 0.125f
#define EPS_ 1e-6f
#define EPSN_ (1e-6f / 1024.0f)
#define C2_ (0.125f * 1.4426950408889634f)   // SCALE * log2(e)

typedef unsigned short u16;
typedef unsigned int u32;
typedef __attribute__((ext_vector_type(8))) short short8;
typedef __attribute__((ext_vector_type(8))) unsigned short ushort8;
typedef __attribute__((ext_vector_type(4))) unsigned short ushort4v;
typedef __attribute__((ext_vector_type(2))) unsigned int uint2v;
typedef __attribute__((ext_vector_type(4))) float f32x4;

__device__ __forceinline__ u16 f2b(float f) {
    union { float f; unsigned u; } v; v.f = f;
    unsigned r = v.u + 0x7fffu + ((v.u >> 16) & 1u);
    return (u16)(r >> 16);
}

__device__ __forceinline__ u32 cvtpk(float lo, float hi) {
    u32 r;
    asm("v_cvt_pk_bf16_f32 %0, %1, %2" : "=v"(r) : "v"(lo), "v"(hi));
    return r;
}

__device__ __forceinline__ f32x4 mfma16(short8 a, short8 b, f32x4 c) {
    return __builtin_amdgcn_mfma_f32_16x16x32_bf16(a, b, c, 0, 0, 0);
}

__device__ __forceinline__ void gload16(const u16* g, u16* l) {
    __builtin_amdgcn_global_load_lds(
        (const __attribute__((address_space(1))) void*)g,
        (__attribute__((address_space(3))) void*)l, 16, 0, 0);
}

// ---- shared pipeline macros ----
#define WAITB(n) do {                                         \
    asm volatile("s_waitcnt vmcnt(" #n ")" ::: "memory");     \
    __builtin_amdgcn_s_barrier();                             \
    asm volatile("" ::: "memory");                            \
} while (0)

#define ENDB do {                                             \
    asm volatile("" ::: "memory");                            \
    __builtin_amdgcn_s_barrier();                             \
} while (0)

// fused prep: LDS-tiled transposes (both sides coalesced) + x->bf16 cvt.
__global__ __launch_bounds__(256) void prep(
    const float* __restrict__ W_qkv, const float* __restrict__ W_out,
    const float* __restrict__ x,
    u16* __restrict__ wqkvT, u16* __restrict__ woutT, u16* __restrict__ Xb) {
    __shared__ float tl[64][65];
    const int t = threadIdx.x;
    const int blk = blockIdx.x;
    if (blk < 256) {
        const float* in; u16* out; int R, C, bx, by;
        if (blk < 192) { in = W_qkv; out = wqkvT; R = 512; C = 1536; bx = blk % 24; by = blk / 24; }
        else           { in = W_out; out = woutT; R = 512; C = 512;  bx = (blk - 192) & 7; by = (blk - 192) >> 3; }
        const int r0 = by * 64, c0 = bx * 64;
        const int rsub = t >> 6, col = t & 63;
#pragma unroll
        for (int k = 0; k < 16; ++k) {
            int row = k * 4 + rsub;
            tl[row][col] = in[(size_t)(r0 + row) * C + c0 + col];
        }
        __syncthreads();
#pragma unroll
        for (int k = 0; k < 16; ++k) {
            int orow = k * 4 + rsub;
            int ocol = col;
            out[(size_t)(c0 + orow) * R + r0 + ocol] = f2b(tl[ocol][orow]);
        }
    } else {
        int i2 = (blk - 256) * 2048 + t * 8;
        float4 f0 = *(const float4*)(x + i2);
        float4 f1 = *(const float4*)(x + i2 + 4);
        ushort8 o;
        o[0]=f2b(f0.x); o[1]=f2b(f0.y); o[2]=f2b(f0.z); o[3]=f2b(f0.w);
        o[4]=f2b(f1.x); o[5]=f2b(f1.y); o[6]=f2b(f1.z); o[7]=f2b(f1.w);
        *(ushort8*)(Xb + i2) = o;
    }
}

// ---- 128x128 tile, BK=64 GEMM pipeline (shared by gemm_qkv / gemm_out) ----
#define GSTAGE(buf, k0) do {                                                  \
    _Pragma("unroll")                                                         \
    for (int call = 0; call < 4; ++call) {                                    \
        const int rr2 = call * 32 + srow;                                     \
        gload16(Xb + (size_t)(rowbase + rr2) * DIM_ + (k0) + sch * 8,         \
                Alf + (buf) * 8192 + call * 2048 + t * 8);                    \
        gload16(BT + (size_t)(colbase + rr2) * DIM_ + (k0) + sch * 8,         \
                Blf + (buf) * 8192 + call * 2048 + t * 8);                    \
    }                                                                         \
} while (0)

#define QCOMP(bsel) do {                                                      \
    _Pragma("unroll")                                                         \
    for (int kk = 0; kk < 64; kk += 32) {                                     \
        short8 af[4], bf[4];                                                  \
        _Pragma("unroll")                                                     \
        for (int m = 0; m < 4; ++m) {                                         \
            const int ar = wr * 64 + m * 16 + lr;                             \
            const int slot = ((kk >> 3) + lg) ^ (lr & 7);                     \
            af[m] = *(const short8*)&Alf[(bsel) * 8192 + ar * 64 + slot * 8]; \
        }                                                                     \
        _Pragma("unroll")                                                     \
        for (int n = 0; n < 4; ++n) {                                         \
            const int br = wc * 64 + n * 16 + lr;                             \
            const int slot = ((kk >> 3) + lg) ^ (lr & 7);                     \
            bf[n] = *(const short8*)&Blf[(bsel) * 8192 + br * 64 + slot * 8]; \
        }                                                                     \
        _Pragma("unroll")                                                     \
        for (int m = 0; m < 4; ++m)                                           \
            _Pragma("unroll")                                                 \
            for (int n = 0; n < 4; ++n)                                       \
                acc[m][n] = mfma16(af[m], bf[n], acc[m][n]);                  \
    }                                                                         \
} while (0)

#define GEMM_PIPE do {                                                        \
    GSTAGE(0, 0);                                                             \
    GSTAGE(1, 64);  WAITB(8); QCOMP(0); ENDB;                                 \
    GSTAGE(0, 128); WAITB(8); QCOMP(1); ENDB;                                 \
    GSTAGE(1, 192); WAITB(8); QCOMP(0); ENDB;                                 \
    GSTAGE(0, 256); WAITB(8); QCOMP(1); ENDB;                                 \
    GSTAGE(1, 320); WAITB(8); QCOMP(0); ENDB;                                 \
    GSTAGE(0, 384); WAITB(8); QCOMP(1); ENDB;                                 \
    GSTAGE(1, 448); WAITB(8); QCOMP(0); ENDB;                                 \
    WAITB(0); QCOMP(1);                                                       \
} while (0)

__global__ __launch_bounds__(256, 2) void gemm_qkv(
    const u16* __restrict__ Xb, const u16* __restrict__ BT,
    u16* __restrict__ Qw, u16* __restrict__ Kw, u16* __restrict__ Vt) {
    __shared__ u16 Al[2 * 8192];
    __shared__ u16 Bl[2 * 8192];
    u16* Alf = &Al[0];
    u16* Blf = &Bl[0];
    const int t = threadIdx.x;
    const int w = t >> 6, l = t & 63, lg = l >> 4, lr = l & 15;
    const int wr = w >> 1, wc = w & 1;
    const int rowbase = blockIdx.y * 128, colbase = blockIdx.x * 128;
    const int srow = t >> 3;
    const int sch = (t & 7) ^ (srow & 7);

    f32x4 acc[4][4];
#pragma unroll
    for (int m = 0; m < 4; m++)
#pragma unroll
        for (int n = 0; n < 4; n++) acc[m][n] = (f32x4){0.f, 0.f, 0.f, 0.f};

    GEMM_PIPE;

#pragma unroll
    for (int m = 0; m < 4; m++) {
#pragma unroll
        for (int n = 0; n < 4; n++) {
#pragma unroll
            for (int j = 0; j < 4; j++) {
                int token = rowbase + wr * 64 + m * 16 + 4 * lg + j;
                int b = token >> 10, nn = token & (N_ - 1);
                int c = colbase + wc * 64 + n * 16 + lr;
                u16 v = f2b(acc[m][n][j]);
                if (c < 512) {
                    int h = c >> 6, d = c & 63;
                    Qw[((size_t)(b * H_ + h) * N_ + nn) * DH_ + d] = v;
                } else if (c < 1024) {
                    int c2 = c - 512, h = c2 >> 6, d = c2 & 63;
                    Kw[((size_t)(b * H_ + h) * N_ + nn) * DH_ + d] = v;
                } else {
                    int c2 = c - 1024, h = c2 >> 6, d = c2 & 63;
                    Vt[((size_t)(b * H_ + h) * DH_ + d) * N_ + nn] = v;
                }
            }
        }
    }
}

// A [8192][512] @ BT [512][512] (+bias) -> out f32, same pipeline
__global__ __launch_bounds__(256, 2) void gemm_out(
    const u16* __restrict__ Xb, const u16* __restrict__ BT,
    const float* __restrict__ bout, float* __restrict__ out) {
    __shared__ u16 Al[2 * 8192];
    __shared__ u16 Bl[2 * 8192];
    u16* Alf = &Al[0];
    u16* Blf = &Bl[0];
    const int t = threadIdx.x;
    const int w = t >> 6, l = t & 63, lg = l >> 4, lr = l & 15;
    const int wr = w >> 1, wc = w & 1;
    const int rowbase = blockIdx.y * 128, colbase = blockIdx.x * 128;
    const int srow = t >> 3;
    const int sch = (t & 7) ^ (srow & 7);

    f32x4 acc[4][4];
#pragma unroll
    for (int m = 0; m < 4; m++)
#pragma unroll
        for (int n = 0; n < 4; n++) acc[m][n] = (f32x4){0.f, 0.f, 0.f, 0.f};

    GEMM_PIPE;

#pragma unroll
    for (int n = 0; n < 4; n++) {
        const int cc = colbase + wc * 64 + n * 16 + lr;
        const float bv = bout[cc];
#pragma unroll
        for (int m = 0; m < 4; m++) {
#pragma unroll
            for (int j = 0; j < 4; j++) {
                int token = rowbase + wr * 64 + m * 16 + 4 * lg + j;
                out[(size_t)token * DIM_ + cc] = acc[m][n][j] + bv;
            }
        }
    }
}

// ---- attn pass 1 kernel: row sums only, high occupancy ----
#define STAGE_K2(c2) do {                                                     \
    gload16(Kb + ((size_t)((c2) * 128 + srow_)) * 64 + sch_ * 8,              \
            SH + ((c2) & 1) * 8192 + t * 8);                                  \
    gload16(Kb + ((size_t)((c2) * 128 + 64 + srow_)) * 64 + sch_ * 8,         \
            SH + ((c2) & 1) * 8192 + 4096 + t * 8);                           \
} while (0)

#define SUM128(c2) do {                                                       \
    _Pragma("unroll")                                                         \
    for (int sub = 0; sub < 8; ++sub) {                                       \
        const u16* kb = SH + ((c2) & 1) * 8192 + (sub >> 2) * 4096            \
                        + ((sub & 3) * 16 + lr) * 64;                         \
        short8 kf0 = *(const short8*)(kb + kswz);                             \
        short8 kf1 = *(const short8*)(kb + (kswz ^ 32));                      \
        f32x4 d = {0.f, 0.f, 0.f, 0.f};                                       \
        d = mfma16(kf0, qf0, d);                                              \
        d = mfma16(kf1, qf1, d);                                              \
        const int kb2 = (c2) * 128 + sub * 16 + 4 * lg;                       \
        ushort4v mv = *(const ushort4v*)&maskL[kb2];                          \
        _Pragma("unroll")                                                     \
        for (int j = 0; j < 4; ++j) {                                         \
            float E = __builtin_amdgcn_exp2f(d[j] * C2_);                     \
            float mm = (mv[j] || (kb2 + j == q)) ? 1.f : 0.f;                 \
            sp += E;                                                          \
            so = fmaf(E, mm, so);                                             \
        }                                                                     \
    }                                                                         \
} while (0)

// 512 blocks x 8 waves; LB(512,4): cap 64 (pass-1 state ~45) -> 4 blocks/CU.
__global__ __launch_bounds__(512, 4) void attn_p1(
    const u16* __restrict__ Qw, const u16* __restrict__ Kw,
    const float* __restrict__ policy,
    float* __restrict__ rip_g, float* __restrict__ rpo_g) {
    __shared__ u16 SH[16384];
    __shared__ u16 maskL[N_];

    const int t = threadIdx.x;
    const int wid = t >> 6, l = t & 63, lg = (l >> 4), lr = l & 15;
    const int srow_ = t >> 3, sch_ = (t & 7) ^ ((t >> 3) & 7);
    const int kswz = (lg ^ (lr & 7)) * 8;

    const int bid = blockIdx.x;              // 512 = 8 xcd * 64
    const int xcd = bid & 7, rr = bid >> 3;
    const int g = rr >> 3, rt = rr & 7;
    const int bh = g * 8 + xcd;
    const int b = bh >> 3;
    const int n0 = rt * 128 + wid * 16;
    const int q = n0 + lr;

    const u16* Qb = Qw + ((size_t)bh * N_ + n0) * DH_;
    const u16* Kb = Kw + (size_t)bh * N_ * DH_;
    const float* pol = policy + b * N_;

    short8 qf0 = *(const short8*)(Qb + lr * DH_ + 8 * lg);
    short8 qf1 = *(const short8*)(Qb + lr * DH_ + 32 + 8 * lg);

    {
        float2 pv = *(const float2*)(pol + t * 2);
        maskL[t * 2 + 0] = pv.x > 0.5f ? 1 : 0;
        maskL[t * 2 + 1] = pv.y > 0.5f ? 1 : 0;
    }
    __syncthreads();   // drains vmcnt(0) -> ledger clean below

    float sp = 0.f, so = 0.f;
    STAGE_K2(0);
#define ITER1(c2, n) do { STAGE_K2(n); WAITB(2); SUM128(c2); ENDB; } while (0)
    ITER1(0, 1); ITER1(1, 2); ITER1(2, 3); ITER1(3, 4);
    ITER1(4, 5); ITER1(5, 6); ITER1(6, 7);
    WAITB(0); SUM128(7);

    sp += __shfl_xor(sp, 16); sp += __shfl_xor(sp, 32);
    so += __shfl_xor(so, 16); so += __shfl_xor(so, 32);
    if (l < 16) {
        rip_g[(size_t)bh * N_ + n0 + lr] = 1.f / sp;
        rpo_g[(size_t)bh * N_ + n0 + lr] = 1.f / (so + EPS_);
    }
}

// ---- attn pass 2 kernel (R14 schedule verbatim; rip/rpo from global) ----
#define STAGE_K(c) gload16(Kb + ((size_t)((c) * 64 + srow_)) * 64 + sch_ * 8, \
                           SH + ((c) & 1) * 4096 + t * 8)
#define STAGE_V(c) gload16(Vb + (size_t)srow_ * N_ + (c) * 64 + sch_ * 8,     \
                           SH + 8192 + ((c) & 1) * 4096 + t * 8)

#define QKTILE(c) do {                                                        \
    _Pragma("unroll")                                                         \
    for (int sub = 0; sub < 4; ++sub) {                                       \
        const u16* kb = SH + ((c) & 1) * 4096 + (sub * 16 + lr) * 64;         \
        short8 kf0 = *(const short8*)(kb + kswz);                             \
        short8 kf1 = *(const short8*)(kb + (kswz ^ 32));                      \
        f32x4 d = {0.f, 0.f, 0.f, 0.f};                                       \
        d = mfma16(kf0, qf0, d);                                              \
        d = mfma16(kf1, qf1, d);                                              \
        const int kb2 = (c) * 64 + sub * 16 + 4 * lg;                         \
        ushort4v mv = *(const ushort4v*)&maskL[kb2];                          \
        f32x4 ov; float p[4];                                                 \
        _Pragma("unroll")                                                     \
        for (int j = 0; j < 4; ++j) {                                         \
            float E = __builtin_amdgcn_exp2f(d[j] * C2_);                     \
            ov[j] = E * rip;                                                  \
            float mm = (mv[j] || (kb2 + j == q)) ? 1.f : 0.f;                 \
            p[j] = fmaf(E * mm, rpo, eb);                                     \
        }                                                                     \
        uint2v wv2;                                                           \
        wv2[0] = cvtpk(p[0], p[1]);                                           \
        wv2[1] = cvtpk(p[2], p[3]);                                           \
        *(f32x4*)(srow + (c) * 64 + sub * 16 + 4 * lg) = ov;                  \
        *(uint2v*)&wl[wid][lr][sub * 16 + 4 * lg] = wv2;                      \
    }                                                                         \
} while (0)

#define PVTILE(c) do {                                                        \
    __builtin_amdgcn_s_setprio(1);                                            \
    _Pragma("unroll")                                                         \
    for (int ks = 0; ks < 64; ks += 32) {                                     \
        short8 af = *(const short8*)&wl[wid][lr][ks + 8 * lg];                \
        _Pragma("unroll")                                                     \
        for (int dt = 0; dt < 4; ++dt) {                                      \
            const u16* vb = SH + 8192 + ((c) & 1) * 4096 + (dt * 16 + lr) * 64; \
            short8 vf = *(const short8*)(vb + (ks ? (kswz ^ 32) : kswz));     \
            apv[dt] = mfma16(af, vf, apv[dt]);                                \
        }                                                                     \
    }                                                                         \
    __builtin_amdgcn_s_setprio(0);                                            \
} while (0)

__global__ __launch_bounds__(512, 2) void attn_p2(
    const u16* __restrict__ Qw, const u16* __restrict__ Kw, const u16* __restrict__ Vt,
    const float* __restrict__ policy,
    const float* __restrict__ rip_g, const float* __restrict__ rpo_g,
    u16* __restrict__ outpre, float* __restrict__ softout) {
    __shared__ u16 SH[16384];      // K dbuf 2x8KB | V dbuf 2x8KB
    __shared__ u16 wl[8][16][72];
    __shared__ u16 maskL[N_];

    const int t = threadIdx.x;
    const int wid = t >> 6, l = t & 63, lg = (l >> 4), lr = l & 15;
    const int srow_ = t >> 3, sch_ = (t & 7) ^ ((t >> 3) & 7);
    const int kswz = (lg ^ (lr & 7)) * 8;

    const int bid = blockIdx.x;              // 512 = 8 xcd * 64
    const int xcd = bid & 7, rr = bid >> 3;
    const int g = rr >> 3, rt = rr & 7;
    const int bh = g * 8 + xcd;
    const int b = bh >> 3, h = bh & 7;
    const int n0 = rt * 128 + wid * 16;
    const int q = n0 + lr;

    const u16* Qb = Qw + ((size_t)bh * N_ + n0) * DH_;
    const u16* Kb = Kw + (size_t)bh * N_ * DH_;
    const u16* Vb = Vt + (size_t)bh * DH_ * N_;
    const float* pol = policy + b * N_;

    short8 qf0 = *(const short8*)(Qb + lr * DH_ + 8 * lg);
    short8 qf1 = *(const short8*)(Qb + lr * DH_ + 32 + 8 * lg);
    const float rip = rip_g[(size_t)bh * N_ + q];
    const float rpo = rpo_g[(size_t)bh * N_ + q];
    const float eb = EPSN_ * rpo;

    {
        float2 pv = *(const float2*)(pol + t * 2);
        maskL[t * 2 + 0] = pv.x > 0.5f ? 1 : 0;
        maskL[t * 2 + 1] = pv.y > 0.5f ? 1 : 0;
    }
    __syncthreads();   // drains vmcnt(0) -> ledger clean below

    f32x4 apv[4];
#pragma unroll
    for (int i = 0; i < 4; i++) apv[i] = (f32x4){0, 0, 0, 0};
    float* srow = softout + ((size_t)bh * N_ + q) * N_;

    STAGE_K(0); STAGE_V(0);
    // c=0: outstanding S0(2)+S1(2) -> wait S0 => vmcnt(2)
    STAGE_K(1); STAGE_V(1); WAITB(2); QKTILE(0); PVTILE(0); ENDB;
    // c=1..14: younger-than-S(c) = stores(4)+S(c+1)(2) => vmcnt(6)
#define ITER2(c, n) do { STAGE_K(n); STAGE_V(n); WAITB(6); QKTILE(c); PVTILE(c); ENDB; } while (0)
    ITER2(1, 2);  ITER2(2, 3);  ITER2(3, 4);  ITER2(4, 5);
    ITER2(5, 6);  ITER2(6, 7);  ITER2(7, 8);  ITER2(8, 9);
    ITER2(9, 10); ITER2(10, 11); ITER2(11, 12); ITER2(12, 13);
    ITER2(13, 14); ITER2(14, 15);
    // c=15: younger-than-S15 = stores_c14(4) => vmcnt(4)
    WAITB(4); QKTILE(15); PVTILE(15);

#pragma unroll
    for (int dt = 0; dt < 4; dt++) {
#pragma unroll
        for (int j = 0; j < 4; j++) {
            outpre[(size_t)(b * N_ + n0 + 4 * lg + j) * DIM_ + h * DH_ + dt * 16 + lr]
                = f2b(apv[dt][j]);
        }
    }
}

extern "C" void kernel_launch(void* const* d_in, const int* in_sizes, int n_in,
                              void* d_out, int out_size, void* d_ws, size_t ws_size,
                              hipStream_t stream) {
    const float* x      = (const float*)d_in[0];
    const float* policy = (const float*)d_in[1];
    const float* W_qkv  = (const float*)d_in[2];
    const float* W_out  = (const float*)d_in[3];
    const float* b_out  = (const float*)d_in[4];
    float* out = (float*)d_out;
    float* softout = out + (size_t)B_ * N_ * DIM_;

    // ws: wqkvT 1.5M | woutT .5M | Xb 8M | Qw 8M | Kw 8M | Vt 8M | pre 8M | rip 256K | rpo 256K
    char* ws = (char*)d_ws;
    u16* wqkvT = (u16*)ws;
    u16* woutT = (u16*)(ws + 1572864);
    u16* Xb    = (u16*)(ws + 2097152);
    u16* Qw    = (u16*)(ws + 10485760);
    u16* Kw    = (u16*)(ws + 18874368);
    u16* Vt    = (u16*)(ws + 27262976);
    u16* pre   = (u16*)(ws + 35651584);
    float* rip_g = (float*)(ws + 44040192);
    float* rpo_g = (float*)(ws + 44302336);

    prep<<<2304, 256, 0, stream>>>(W_qkv, W_out, x, wqkvT, woutT, Xb);
    gemm_qkv<<<dim3(12, 64), 256, 0, stream>>>(Xb, wqkvT, Qw, Kw, Vt);
    attn_p1<<<512, 512, 0, stream>>>(Qw, Kw, policy, rip_g, rpo_g);
    attn_p2<<<512, 512, 0, stream>>>(Qw, Kw, Vt, policy, rip_g, rpo_g, pre, softout);
    gemm_out<<<dim3(4, 64), 256, 0, stream>>>(pre, woutT, b_out, out);
}

// Round 18
// 145.965 us; speedup vs baseline: 1.6713x; 1.1492x over previous
//
#include <hip/hip_runtime.h>

#define B_ 8
#define N_ 1024
#define DIM_ 512
#define H_ 8
#define DH_ 64
#define SCALE_ 0.125f
#define EPS_ 1e-6f
#define EPSN_ (1e-6f / 1024.0f)
#define C2_ (0.125f * 1.4426950408889634f)   // SCALE * log2(e)

typedef unsigned short u16;
typedef unsigned int u32;
typedef __attribute__((ext_vector_type(8))) short short8;
typedef __attribute__((ext_vector_type(8))) unsigned short ushort8;
typedef __attribute__((ext_vector_type(4))) unsigned short ushort4v;
typedef __attribute__((ext_vector_type(2))) unsigned int uint2v;
typedef __attribute__((ext_vector_type(4))) float f32x4;

__device__ __forceinline__ u16 f2b(float f) {
    union { float f; unsigned u; } v; v.f = f;
    unsigned r = v.u + 0x7fffu + ((v.u >> 16) & 1u);
    return (u16)(r >> 16);
}

__device__ __forceinline__ u32 cvtpk(float lo, float hi) {
    u32 r;
    asm("v_cvt_pk_bf16_f32 %0, %1, %2" : "=v"(r) : "v"(lo), "v"(hi));
    return r;
}

__device__ __forceinline__ f32x4 mfma16(short8 a, short8 b, f32x4 c) {
    return __builtin_amdgcn_mfma_f32_16x16x32_bf16(a, b, c, 0, 0, 0);
}

__device__ __forceinline__ void gload16(const u16* g, u16* l) {
    __builtin_amdgcn_global_load_lds(
        (const __attribute__((address_space(1))) void*)g,
        (__attribute__((address_space(3))) void*)l, 16, 0, 0);
}

// ---- shared pipeline macros ----
#define WAITB(n) do {                                         \
    asm volatile("s_waitcnt vmcnt(" #n ")" ::: "memory");     \
    __builtin_amdgcn_s_barrier();                             \
    asm volatile("" ::: "memory");                            \
} while (0)

#define ENDB do {                                             \
    asm volatile("" ::: "memory");                            \
    __builtin_amdgcn_s_barrier();                             \
} while (0)

// fused prep: LDS-tiled transposes (both sides coalesced) + x->bf16 cvt.
__global__ __launch_bounds__(256) void prep(
    const float* __restrict__ W_qkv, const float* __restrict__ W_out,
    const float* __restrict__ x,
    u16* __restrict__ wqkvT, u16* __restrict__ woutT, u16* __restrict__ Xb) {
    __shared__ float tl[64][65];
    const int t = threadIdx.x;
    const int blk = blockIdx.x;
    if (blk < 256) {
        const float* in; u16* out; int R, C, bx, by;
        if (blk < 192) { in = W_qkv; out = wqkvT; R = 512; C = 1536; bx = blk % 24; by = blk / 24; }
        else           { in = W_out; out = woutT; R = 512; C = 512;  bx = (blk - 192) & 7; by = (blk - 192) >> 3; }
        const int r0 = by * 64, c0 = bx * 64;
        const int rsub = t >> 6, col = t & 63;
#pragma unroll
        for (int k = 0; k < 16; ++k) {
            int row = k * 4 + rsub;
            tl[row][col] = in[(size_t)(r0 + row) * C + c0 + col];
        }
        __syncthreads();
#pragma unroll
        for (int k = 0; k < 16; ++k) {
            int orow = k * 4 + rsub;
            int ocol = col;
            out[(size_t)(c0 + orow) * R + r0 + ocol] = f2b(tl[ocol][orow]);
        }
    } else {
        int i2 = (blk - 256) * 2048 + t * 8;
        float4 f0 = *(const float4*)(x + i2);
        float4 f1 = *(const float4*)(x + i2 + 4);
        ushort8 o;
        o[0]=f2b(f0.x); o[1]=f2b(f0.y); o[2]=f2b(f0.z); o[3]=f2b(f0.w);
        o[4]=f2b(f1.x); o[5]=f2b(f1.y); o[6]=f2b(f1.z); o[7]=f2b(f1.w);
        *(ushort8*)(Xb + i2) = o;
    }
}

// ---- 128x128 tile, BK=64 GEMM pipeline (shared by gemm_qkv / gemm_out) ----
#define GSTAGE(buf, k0) do {                                                  \
    _Pragma("unroll")                                                         \
    for (int call = 0; call < 4; ++call) {                                    \
        const int rr2 = call * 32 + srow;                                     \
        gload16(Xb + (size_t)(rowbase + rr2) * DIM_ + (k0) + sch * 8,         \
                Alf + (buf) * 8192 + call * 2048 + t * 8);                    \
        gload16(BT + (size_t)(colbase + rr2) * DIM_ + (k0) + sch * 8,         \
                Blf + (buf) * 8192 + call * 2048 + t * 8);                    \
    }                                                                         \
} while (0)

#define QCOMP(bsel) do {                                                      \
    _Pragma("unroll")                                                         \
    for (int kk = 0; kk < 64; kk += 32) {                                     \
        short8 af[4], bf[4];                                                  \
        _Pragma("unroll")                                                     \
        for (int m = 0; m < 4; ++m) {                                         \
            const int ar = wr * 64 + m * 16 + lr;                             \
            const int slot = ((kk >> 3) + lg) ^ (lr & 7);                     \
            af[m] = *(const short8*)&Alf[(bsel) * 8192 + ar * 64 + slot * 8]; \
        }                                                                     \
        _Pragma("unroll")                                                     \
        for (int n = 0; n < 4; ++n) {                                         \
            const int br = wc * 64 + n * 16 + lr;                             \
            const int slot = ((kk >> 3) + lg) ^ (lr & 7);                     \
            bf[n] = *(const short8*)&Blf[(bsel) * 8192 + br * 64 + slot * 8]; \
        }                                                                     \
        _Pragma("unroll")                                                     \
        for (int m = 0; m < 4; ++m)                                           \
            _Pragma("unroll")                                                 \
            for (int n = 0; n < 4; ++n)                                       \
                acc[m][n] = mfma16(af[m], bf[n], acc[m][n]);                  \
    }                                                                         \
} while (0)

#define GEMM_PIPE do {                                                        \
    GSTAGE(0, 0);                                                             \
    GSTAGE(1, 64);  WAITB(8); QCOMP(0); ENDB;                                 \
    GSTAGE(0, 128); WAITB(8); QCOMP(1); ENDB;                                 \
    GSTAGE(1, 192); WAITB(8); QCOMP(0); ENDB;                                 \
    GSTAGE(0, 256); WAITB(8); QCOMP(1); ENDB;                                 \
    GSTAGE(1, 320); WAITB(8); QCOMP(0); ENDB;                                 \
    GSTAGE(0, 384); WAITB(8); QCOMP(1); ENDB;                                 \
    GSTAGE(1, 448); WAITB(8); QCOMP(0); ENDB;                                 \
    WAITB(0); QCOMP(1);                                                       \
} while (0)

__global__ __launch_bounds__(256, 2) void gemm_qkv(
    const u16* __restrict__ Xb, const u16* __restrict__ BT,
    u16* __restrict__ Qw, u16* __restrict__ Kw, u16* __restrict__ Vt) {
    __shared__ u16 Al[2 * 8192];
    __shared__ u16 Bl[2 * 8192];
    u16* Alf = &Al[0];
    u16* Blf = &Bl[0];
    const int t = threadIdx.x;
    const int w = t >> 6, l = t & 63, lg = l >> 4, lr = l & 15;
    const int wr = w >> 1, wc = w & 1;
    const int rowbase = blockIdx.y * 128, colbase = blockIdx.x * 128;
    const int srow = t >> 3;
    const int sch = (t & 7) ^ (srow & 7);

    f32x4 acc[4][4];
#pragma unroll
    for (int m = 0; m < 4; m++)
#pragma unroll
        for (int n = 0; n < 4; n++) acc[m][n] = (f32x4){0.f, 0.f, 0.f, 0.f};

    GEMM_PIPE;

#pragma unroll
    for (int m = 0; m < 4; m++) {
#pragma unroll
        for (int n = 0; n < 4; n++) {
#pragma unroll
            for (int j = 0; j < 4; j++) {
                int token = rowbase + wr * 64 + m * 16 + 4 * lg + j;
                int b = token >> 10, nn = token & (N_ - 1);
                int c = colbase + wc * 64 + n * 16 + lr;
                u16 v = f2b(acc[m][n][j]);
                if (c < 512) {
                    int h = c >> 6, d = c & 63;
                    Qw[((size_t)(b * H_ + h) * N_ + nn) * DH_ + d] = v;
                } else if (c < 1024) {
                    int c2 = c - 512, h = c2 >> 6, d = c2 & 63;
                    Kw[((size_t)(b * H_ + h) * N_ + nn) * DH_ + d] = v;
                } else {
                    int c2 = c - 1024, h = c2 >> 6, d = c2 & 63;
                    Vt[((size_t)(b * H_ + h) * DH_ + d) * N_ + nn] = v;
                }
            }
        }
    }
}

// A [8192][512] @ BT [512][512] (+bias) -> out f32, same pipeline
__global__ __launch_bounds__(256, 2) void gemm_out(
    const u16* __restrict__ Xb, const u16* __restrict__ BT,
    const float* __restrict__ bout, float* __restrict__ out) {
    __shared__ u16 Al[2 * 8192];
    __shared__ u16 Bl[2 * 8192];
    u16* Alf = &Al[0];
    u16* Blf = &Bl[0];
    const int t = threadIdx.x;
    const int w = t >> 6, l = t & 63, lg = l >> 4, lr = l & 15;
    const int wr = w >> 1, wc = w & 1;
    const int rowbase = blockIdx.y * 128, colbase = blockIdx.x * 128;
    const int srow = t >> 3;
    const int sch = (t & 7) ^ (srow & 7);

    f32x4 acc[4][4];
#pragma unroll
    for (int m = 0; m < 4; m++)
#pragma unroll
        for (int n = 0; n < 4; n++) acc[m][n] = (f32x4){0.f, 0.f, 0.f, 0.f};

    GEMM_PIPE;

#pragma unroll
    for (int n = 0; n < 4; n++) {
        const int cc = colbase + wc * 64 + n * 16 + lr;
        const float bv = bout[cc];
#pragma unroll
        for (int m = 0; m < 4; m++) {
#pragma unroll
            for (int j = 0; j < 4; j++) {
                int token = rowbase + wr * 64 + m * 16 + 4 * lg + j;
                out[(size_t)token * DIM_ + cc] = acc[m][n][j] + bv;
            }
        }
    }
}

// ---- attn macros ----
// sweep A: 64-col phases; K dbuf SH[0..8191], V dbuf SH[8192..16383]
#define STAGE_K(c) gload16(Kb + ((size_t)((c) * 64 + srow_)) * 64 + sch_ * 8, \
                           SH + ((c) & 1) * 4096 + t * 8)
#define STAGE_V(c) gload16(Vb + (size_t)srow_ * N_ + (c) * 64 + sch_ * 8,     \
                           SH + 8192 + ((c) & 1) * 4096 + t * 8)

// QK + sums + pack P' = E*mm + EPSN (no rpo!) + PV. No global stores.
#define QPV(c) do {                                                           \
    _Pragma("unroll")                                                         \
    for (int sub = 0; sub < 4; ++sub) {                                       \
        const u16* kb = SH + ((c) & 1) * 4096 + (sub * 16 + lr) * 64;         \
        short8 kf0 = *(const short8*)(kb + kswz);                             \
        short8 kf1 = *(const short8*)(kb + (kswz ^ 32));                      \
        f32x4 d = {0.f, 0.f, 0.f, 0.f};                                       \
        d = mfma16(kf0, qf0, d);                                              \
        d = mfma16(kf1, qf1, d);                                              \
        const int kb2 = (c) * 64 + sub * 16 + 4 * lg;                         \
        ushort4v mv = *(const ushort4v*)&maskL[kb2];                          \
        float p[4];                                                           \
        _Pragma("unroll")                                                     \
        for (int j = 0; j < 4; ++j) {                                         \
            float E = __builtin_amdgcn_exp2f(d[j] * C2_);                     \
            float mm = (mv[j] || (kb2 + j == q)) ? 1.f : 0.f;                 \
            float em = E * mm;                                                \
            sp += E;                                                          \
            so += em;                                                         \
            p[j] = em + EPSN_;                                                \
        }                                                                     \
        uint2v wv2;                                                           \
        wv2[0] = cvtpk(p[0], p[1]);                                           \
        wv2[1] = cvtpk(p[2], p[3]);                                           \
        *(uint2v*)&wl[wid][lr][sub * 16 + 4 * lg] = wv2;                      \
    }                                                                         \
    __builtin_amdgcn_s_setprio(1);                                            \
    _Pragma("unroll")                                                         \
    for (int ks = 0; ks < 64; ks += 32) {                                     \
        short8 af = *(const short8*)&wl[wid][lr][ks + 8 * lg];                \
        _Pragma("unroll")                                                     \
        for (int dt = 0; dt < 4; ++dt) {                                      \
            const u16* vb = SH + 8192 + ((c) & 1) * 4096 + (dt * 16 + lr) * 64; \
            short8 vf = *(const short8*)(vb + (ks ? (kswz ^ 32) : kswz));     \
            apv[dt] = mfma16(af, vf, apv[dt]);                                \
        }                                                                     \
    }                                                                         \
    __builtin_amdgcn_s_setprio(0);                                            \
} while (0)

// sweep B: 128-col K-only phases into 2x16KB dbuf (whole SH)
#define STAGE_K2(c2) do {                                                     \
    gload16(Kb + ((size_t)((c2) * 128 + srow_)) * 64 + sch_ * 8,              \
            SH + ((c2) & 1) * 8192 + t * 8);                                  \
    gload16(Kb + ((size_t)((c2) * 128 + 64 + srow_)) * 64 + sch_ * 8,         \
            SH + ((c2) & 1) * 8192 + 4096 + t * 8);                           \
} while (0)

// QK + exp + x4 softmax store only. No LDS P, no V, no PV.
#define W128(c2) do {                                                         \
    _Pragma("unroll")                                                         \
    for (int sub = 0; sub < 8; ++sub) {                                       \
        const u16* kb = SH + ((c2) & 1) * 8192 + (sub >> 2) * 4096            \
                        + ((sub & 3) * 16 + lr) * 64;                         \
        short8 kf0 = *(const short8*)(kb + kswz);                             \
        short8 kf1 = *(const short8*)(kb + (kswz ^ 32));                      \
        f32x4 d = {0.f, 0.f, 0.f, 0.f};                                       \
        d = mfma16(kf0, qf0, d);                                              \
        d = mfma16(kf1, qf1, d);                                              \
        f32x4 ov;                                                             \
        _Pragma("unroll")                                                     \
        for (int j = 0; j < 4; ++j)                                           \
            ov[j] = __builtin_amdgcn_exp2f(d[j] * C2_) * rip;                 \
        *(f32x4*)(srow + (c2) * 128 + sub * 16 + 4 * lg) = ov;                \
    }                                                                         \
} while (0)

// 512 blocks x 8 waves (128 q-rows/block), single tranche, XCD-swizzled.
// LB(512,2) = 1 block/CU, VGPR cap 128 (session-measured; 84/64 caps spill).
// Sweep A: sums + PV via O = rpo * sum((E*mm+eps/N) V) -- pure-load vmcnt(2).
// Sweep B: pure softmax-write stream (K-only staging, no wl/V/PV).
__global__ __launch_bounds__(512, 2) void attn_kernel(
    const u16* __restrict__ Qw, const u16* __restrict__ Kw, const u16* __restrict__ Vt,
    const float* __restrict__ policy, u16* __restrict__ outpre, float* __restrict__ softout) {
    __shared__ u16 SH[16384];      // A: K dbuf | V dbuf ; B: K128 dbuf
    __shared__ u16 wl[8][16][72];
    __shared__ u16 maskL[N_];

    const int t = threadIdx.x;
    const int wid = t >> 6, l = t & 63, lg = (l >> 4), lr = l & 15;
    const int srow_ = t >> 3, sch_ = (t & 7) ^ ((t >> 3) & 7);
    const int kswz = (lg ^ (lr & 7)) * 8;

    const int bid = blockIdx.x;              // 512 = 8 xcd * 64
    const int xcd = bid & 7, rr = bid >> 3;
    const int g = rr >> 3, rt = rr & 7;
    const int bh = g * 8 + xcd;
    const int b = bh >> 3, h = bh & 7;
    const int n0 = rt * 128 + wid * 16;
    const int q = n0 + lr;

    const u16* Qb = Qw + ((size_t)bh * N_ + n0) * DH_;
    const u16* Kb = Kw + (size_t)bh * N_ * DH_;
    const u16* Vb = Vt + (size_t)bh * DH_ * N_;
    const float* pol = policy + b * N_;

    short8 qf0 = *(const short8*)(Qb + lr * DH_ + 8 * lg);
    short8 qf1 = *(const short8*)(Qb + lr * DH_ + 32 + 8 * lg);

    {
        float2 pv = *(const float2*)(pol + t * 2);
        maskL[t * 2 + 0] = pv.x > 0.5f ? 1 : 0;
        maskL[t * 2 + 1] = pv.y > 0.5f ? 1 : 0;
    }
    __syncthreads();   // drains vmcnt(0) -> ledger clean below

    // ---- sweep A: row sums + policy-PV (no global stores) ----
    float sp = 0.f, so = 0.f;
    f32x4 apv[4];
#pragma unroll
    for (int i = 0; i < 4; i++) apv[i] = (f32x4){0, 0, 0, 0};

    STAGE_K(0); STAGE_V(0);
    // c=0: newer than S0 = S1(2) => vmcnt(2)
    STAGE_K(1); STAGE_V(1); WAITB(2); QPV(0); ENDB;
    // c=1..14: newer than S(c) = S(c+1)(2) => vmcnt(2)  [no stores in sweep A]
#define ITERA(c, n) do { STAGE_K(n); STAGE_V(n); WAITB(2); QPV(c); ENDB; } while (0)
    ITERA(1, 2);  ITERA(2, 3);  ITERA(3, 4);  ITERA(4, 5);
    ITERA(5, 6);  ITERA(6, 7);  ITERA(7, 8);  ITERA(8, 9);
    ITERA(9, 10); ITERA(10, 11); ITERA(11, 12); ITERA(12, 13);
    ITERA(13, 14); ITERA(14, 15);
    WAITB(0); QPV(15);
    ENDB;   // SH reused by sweep B staging below

    sp += __shfl_xor(sp, 16); sp += __shfl_xor(sp, 32);
    so += __shfl_xor(so, 16); so += __shfl_xor(so, 32);
    const float rip = 1.f / sp;
    const float rpo = 1.f / (so + EPS_);

    // ---- sweep B: plain-softmax write stream (K-only staging) ----
    float* srow = softout + ((size_t)bh * N_ + q) * N_;
    STAGE_K2(0);
    // c2=0: newer than S'0 = S'1(2) => vmcnt(2)
    STAGE_K2(1); WAITB(2); W128(0); ENDB;
    // c2=1..6: newer than S'(c2) = st(c2-1)(8) + S'(c2+1)(2) => vmcnt(10)
#define ITERB(c2, n) do { STAGE_K2(n); WAITB(10); W128(c2); ENDB; } while (0)
    ITERB(1, 2); ITERB(2, 3); ITERB(3, 4);
    ITERB(4, 5); ITERB(5, 6); ITERB(6, 7);
    // c2=7: newer than S'7 = st6(8) => vmcnt(8)
    WAITB(8); W128(7);

    // epilogue: outpre = rpo * apv
#pragma unroll
    for (int dt = 0; dt < 4; dt++) {
#pragma unroll
        for (int j = 0; j < 4; j++) {
            outpre[(size_t)(b * N_ + n0 + 4 * lg + j) * DIM_ + h * DH_ + dt * 16 + lr]
                = f2b(apv[dt][j] * rpo);
        }
    }
}

extern "C" void kernel_launch(void* const* d_in, const int* in_sizes, int n_in,
                              void* d_out, int out_size, void* d_ws, size_t ws_size,
                              hipStream_t stream) {
    const float* x      = (const float*)d_in[0];
    const float* policy = (const float*)d_in[1];
    const float* W_qkv  = (const float*)d_in[2];
    const float* W_out  = (const float*)d_in[3];
    const float* b_out  = (const float*)d_in[4];
    float* out = (float*)d_out;
    float* softout = out + (size_t)B_ * N_ * DIM_;

    // ws: wqkvT 1.5M | woutT .5M | Xb 8M | Qw 8M | Kw 8M | Vt 8M | pre 8M
    char* ws = (char*)d_ws;
    u16* wqkvT = (u16*)ws;
    u16* woutT = (u16*)(ws + 1572864);
    u16* Xb    = (u16*)(ws + 2097152);
    u16* Qw    = (u16*)(ws + 10485760);
    u16* Kw    = (u16*)(ws + 18874368);
    u16* Vt    = (u16*)(ws + 27262976);
    u16* pre   = (u16*)(ws + 35651584);

    prep<<<2304, 256, 0, stream>>>(W_qkv, W_out, x, wqkvT, woutT, Xb);
    gemm_qkv<<<dim3(12, 64), 256, 0, stream>>>(Xb, wqkvT, Qw, Kw, Vt);
    attn_kernel<<<512, 512, 0, stream>>>(Qw, Kw, Vt, policy, pre, softout);
    gemm_out<<<dim3(4, 64), 256, 0, stream>>>(pre, woutT, b_out, out);
}

// Round 19
// 139.305 us; speedup vs baseline: 1.7512x; 1.0478x over previous
//
#include <hip/hip_runtime.h>

#define B_ 8
#define N_ 1024
#define DIM_ 512
#define H_ 8
#define DH_ 64
#define SCALE_ 0.125f
#define EPS_ 1e-6f
#define EPSN_ (1e-6f / 1024.0f)
#define C2_ (0.125f * 1.4426950408889634f)   // SCALE * log2(e)

typedef unsigned short u16;
typedef unsigned int u32;
typedef __attribute__((ext_vector_type(8))) short short8;
typedef __attribute__((ext_vector_type(8))) unsigned short ushort8;
typedef __attribute__((ext_vector_type(4))) unsigned short ushort4v;
typedef __attribute__((ext_vector_type(2))) unsigned int uint2v;
typedef __attribute__((ext_vector_type(4))) float f32x4;

__device__ __forceinline__ u16 f2b(float f) {
    union { float f; unsigned u; } v; v.f = f;
    unsigned r = v.u + 0x7fffu + ((v.u >> 16) & 1u);
    return (u16)(r >> 16);
}

__device__ __forceinline__ u32 cvtpk(float lo, float hi) {
    u32 r;
    asm("v_cvt_pk_bf16_f32 %0, %1, %2" : "=v"(r) : "v"(lo), "v"(hi));
    return r;
}

__device__ __forceinline__ f32x4 mfma16(short8 a, short8 b, f32x4 c) {
    return __builtin_amdgcn_mfma_f32_16x16x32_bf16(a, b, c, 0, 0, 0);
}

__device__ __forceinline__ void gload16(const u16* g, u16* l) {
    __builtin_amdgcn_global_load_lds(
        (const __attribute__((address_space(1))) void*)g,
        (__attribute__((address_space(3))) void*)l, 16, 0, 0);
}

// ---- shared pipeline macros ----
#define WAITB(n) do {                                         \
    asm volatile("s_waitcnt vmcnt(" #n ")" ::: "memory");     \
    __builtin_amdgcn_s_barrier();                             \
    asm volatile("" ::: "memory");                            \
} while (0)

#define ENDB do {                                             \
    asm volatile("" ::: "memory");                            \
    __builtin_amdgcn_s_barrier();                             \
} while (0)

// fused prep: LDS-tiled transposes (both sides coalesced) + x->bf16 cvt.
__global__ __launch_bounds__(256) void prep(
    const float* __restrict__ W_qkv, const float* __restrict__ W_out,
    const float* __restrict__ x,
    u16* __restrict__ wqkvT, u16* __restrict__ woutT, u16* __restrict__ Xb) {
    __shared__ float tl[64][65];
    const int t = threadIdx.x;
    const int blk = blockIdx.x;
    if (blk < 256) {
        const float* in; u16* out; int R, C, bx, by;
        if (blk < 192) { in = W_qkv; out = wqkvT; R = 512; C = 1536; bx = blk % 24; by = blk / 24; }
        else           { in = W_out; out = woutT; R = 512; C = 512;  bx = (blk - 192) & 7; by = (blk - 192) >> 3; }
        const int r0 = by * 64, c0 = bx * 64;
        const int rsub = t >> 6, col = t & 63;
#pragma unroll
        for (int k = 0; k < 16; ++k) {
            int row = k * 4 + rsub;
            tl[row][col] = in[(size_t)(r0 + row) * C + c0 + col];
        }
        __syncthreads();
#pragma unroll
        for (int k = 0; k < 16; ++k) {
            int orow = k * 4 + rsub;
            int ocol = col;
            out[(size_t)(c0 + orow) * R + r0 + ocol] = f2b(tl[ocol][orow]);
        }
    } else {
        int i2 = (blk - 256) * 2048 + t * 8;
        float4 f0 = *(const float4*)(x + i2);
        float4 f1 = *(const float4*)(x + i2 + 4);
        ushort8 o;
        o[0]=f2b(f0.x); o[1]=f2b(f0.y); o[2]=f2b(f0.z); o[3]=f2b(f0.w);
        o[4]=f2b(f1.x); o[5]=f2b(f1.y); o[6]=f2b(f1.z); o[7]=f2b(f1.w);
        *(ushort8*)(Xb + i2) = o;
    }
}

// ---- 128x128 tile, BK=64 GEMM pipeline (shared by gemm_qkv / gemm_out) ----
#define GSTAGE(buf, k0) do {                                                  \
    _Pragma("unroll")                                                         \
    for (int call = 0; call < 4; ++call) {                                    \
        const int rr2 = call * 32 + srow;                                     \
        gload16(Xb + (size_t)(rowbase + rr2) * DIM_ + (k0) + sch * 8,         \
                Alf + (buf) * 8192 + call * 2048 + t * 8);                    \
        gload16(BT + (size_t)(colbase + rr2) * DIM_ + (k0) + sch * 8,         \
                Blf + (buf) * 8192 + call * 2048 + t * 8);                    \
    }                                                                         \
} while (0)

#define QCOMP(bsel) do {                                                      \
    _Pragma("unroll")                                                         \
    for (int kk = 0; kk < 64; kk += 32) {                                     \
        short8 af[4], bf[4];                                                  \
        _Pragma("unroll")                                                     \
        for (int m = 0; m < 4; ++m) {                                         \
            const int ar = wr * 64 + m * 16 + lr;                             \
            const int slot = ((kk >> 3) + lg) ^ (lr & 7);                     \
            af[m] = *(const short8*)&Alf[(bsel) * 8192 + ar * 64 + slot * 8]; \
        }                                                                     \
        _Pragma("unroll")                                                     \
        for (int n = 0; n < 4; ++n) {                                         \
            const int br = wc * 64 + n * 16 + lr;                             \
            const int slot = ((kk >> 3) + lg) ^ (lr & 7);                     \
            bf[n] = *(const short8*)&Blf[(bsel) * 8192 + br * 64 + slot * 8]; \
        }                                                                     \
        _Pragma("unroll")                                                     \
        for (int m = 0; m < 4; ++m)                                           \
            _Pragma("unroll")                                                 \
            for (int n = 0; n < 4; ++n)                                       \
                acc[m][n] = mfma16(af[m], bf[n], acc[m][n]);                  \
    }                                                                         \
} while (0)

#define GEMM_PIPE do {                                                        \
    GSTAGE(0, 0);                                                             \
    GSTAGE(1, 64);  WAITB(8); QCOMP(0); ENDB;                                 \
    GSTAGE(0, 128); WAITB(8); QCOMP(1); ENDB;                                 \
    GSTAGE(1, 192); WAITB(8); QCOMP(0); ENDB;                                 \
    GSTAGE(0, 256); WAITB(8); QCOMP(1); ENDB;                                 \
    GSTAGE(1, 320); WAITB(8); QCOMP(0); ENDB;                                 \
    GSTAGE(0, 384); WAITB(8); QCOMP(1); ENDB;                                 \
    GSTAGE(1, 448); WAITB(8); QCOMP(0); ENDB;                                 \
    WAITB(0); QCOMP(1);                                                       \
} while (0)

__global__ __launch_bounds__(256, 2) void gemm_qkv(
    const u16* __restrict__ Xb, const u16* __restrict__ BT,
    u16* __restrict__ Qw, u16* __restrict__ Kw, u16* __restrict__ Vt) {
    __shared__ u16 Al[2 * 8192];
    __shared__ u16 Bl[2 * 8192];
    u16* Alf = &Al[0];
    u16* Blf = &Bl[0];
    const int t = threadIdx.x;
    const int w = t >> 6, l = t & 63, lg = l >> 4, lr = l & 15;
    const int wr = w >> 1, wc = w & 1;
    const int rowbase = blockIdx.y * 128, colbase = blockIdx.x * 128;
    const int srow = t >> 3;
    const int sch = (t & 7) ^ (srow & 7);

    f32x4 acc[4][4];
#pragma unroll
    for (int m = 0; m < 4; m++)
#pragma unroll
        for (int n = 0; n < 4; n++) acc[m][n] = (f32x4){0.f, 0.f, 0.f, 0.f};

    GEMM_PIPE;

#pragma unroll
    for (int m = 0; m < 4; m++) {
#pragma unroll
        for (int n = 0; n < 4; n++) {
#pragma unroll
            for (int j = 0; j < 4; j++) {
                int token = rowbase + wr * 64 + m * 16 + 4 * lg + j;
                int b = token >> 10, nn = token & (N_ - 1);
                int c = colbase + wc * 64 + n * 16 + lr;
                u16 v = f2b(acc[m][n][j]);
                if (c < 512) {
                    int h = c >> 6, d = c & 63;
                    Qw[((size_t)(b * H_ + h) * N_ + nn) * DH_ + d] = v;
                } else if (c < 1024) {
                    int c2 = c - 512, h = c2 >> 6, d = c2 & 63;
                    Kw[((size_t)(b * H_ + h) * N_ + nn) * DH_ + d] = v;
                } else {
                    int c2 = c - 1024, h = c2 >> 6, d = c2 & 63;
                    Vt[((size_t)(b * H_ + h) * DH_ + d) * N_ + nn] = v;
                }
            }
        }
    }
}

// A [8192][512] @ BT [512][512] (+bias) -> out f32, same pipeline
__global__ __launch_bounds__(256, 2) void gemm_out(
    const u16* __restrict__ Xb, const u16* __restrict__ BT,
    const float* __restrict__ bout, float* __restrict__ out) {
    __shared__ u16 Al[2 * 8192];
    __shared__ u16 Bl[2 * 8192];
    u16* Alf = &Al[0];
    u16* Blf = &Bl[0];
    const int t = threadIdx.x;
    const int w = t >> 6, l = t & 63, lg = l >> 4, lr = l & 15;
    const int wr = w >> 1, wc = w & 1;
    const int rowbase = blockIdx.y * 128, colbase = blockIdx.x * 128;
    const int srow = t >> 3;
    const int sch = (t & 7) ^ (srow & 7);

    f32x4 acc[4][4];
#pragma unroll
    for (int m = 0; m < 4; m++)
#pragma unroll
        for (int n = 0; n < 4; n++) acc[m][n] = (f32x4){0.f, 0.f, 0.f, 0.f};

    GEMM_PIPE;

#pragma unroll
    for (int n = 0; n < 4; n++) {
        const int cc = colbase + wc * 64 + n * 16 + lr;
        const float bv = bout[cc];
#pragma unroll
        for (int m = 0; m < 4; m++) {
#pragma unroll
            for (int j = 0; j < 4; j++) {
                int token = rowbase + wr * 64 + m * 16 + 4 * lg + j;
                out[(size_t)token * DIM_ + cc] = acc[m][n][j] + bv;
            }
        }
    }
}

// ---- attn macros ----
// pass 1: 128-col K tiles into unified 2x16KB dbuf (SH)
#define STAGE_K2(c2) do {                                                     \
    gload16(Kb + ((size_t)((c2) * 128 + srow_)) * 64 + sch_ * 8,              \
            SH + ((c2) & 1) * 8192 + t * 8);                                  \
    gload16(Kb + ((size_t)((c2) * 128 + 64 + srow_)) * 64 + sch_ * 8,         \
            SH + ((c2) & 1) * 8192 + 4096 + t * 8);                           \
} while (0)

#define SUM128(c2) do {                                                       \
    _Pragma("unroll")                                                         \
    for (int sub = 0; sub < 8; ++sub) {                                       \
        const u16* kb = SH + ((c2) & 1) * 8192 + (sub >> 2) * 4096            \
                        + ((sub & 3) * 16 + lr) * 64;                         \
        short8 kf0 = *(const short8*)(kb + kswz);                             \
        short8 kf1 = *(const short8*)(kb + (kswz ^ 32));                      \
        f32x4 d = {0.f, 0.f, 0.f, 0.f};                                       \
        d = mfma16(kf0, qf0, d);                                              \
        d = mfma16(kf1, qf1, d);                                              \
        const int kb2 = (c2) * 128 + sub * 16 + 4 * lg;                       \
        f32x4 m4 = *(const f32x4*)&maskL[kb2];                                \
        _Pragma("unroll")                                                     \
        for (int j = 0; j < 4; ++j) {                                         \
            float E = __builtin_amdgcn_exp2f(d[j] * C2_);                     \
            float mm = (kb2 + j == q) ? 1.f : m4[j];                          \
            sp += E;                                                          \
            so = fmaf(E, mm, so);                                             \
        }                                                                     \
    }                                                                         \
} while (0)

// pass 2 (R13, proven): 64-col phases; K in SH[0..8191], V in SH[8192..]
#define STAGE_K(c) gload16(Kb + ((size_t)((c) * 64 + srow_)) * 64 + sch_ * 8, \
                           SH + ((c) & 1) * 4096 + t * 8)
#define STAGE_V(c) gload16(Vb + (size_t)srow_ * N_ + (c) * 64 + sch_ * 8,     \
                           SH + 8192 + ((c) & 1) * 4096 + t * 8)

#define QKTILE(c) do {                                                        \
    _Pragma("unroll")                                                         \
    for (int sub = 0; sub < 4; ++sub) {                                       \
        const u16* kb = SH + ((c) & 1) * 4096 + (sub * 16 + lr) * 64;         \
        short8 kf0 = *(const short8*)(kb + kswz);                             \
        short8 kf1 = *(const short8*)(kb + (kswz ^ 32));                      \
        f32x4 d = {0.f, 0.f, 0.f, 0.f};                                       \
        d = mfma16(kf0, qf0, d);                                              \
        d = mfma16(kf1, qf1, d);                                              \
        const int kb2 = (c) * 64 + sub * 16 + 4 * lg;                         \
        f32x4 m4 = *(const f32x4*)&maskL[kb2];                                \
        f32x4 ov; float p[4];                                                 \
        _Pragma("unroll")                                                     \
        for (int j = 0; j < 4; ++j) {                                         \
            float E = __builtin_amdgcn_exp2f(d[j] * C2_);                     \
            ov[j] = E * rip;                                                  \
            float mm = (kb2 + j == q) ? 1.f : m4[j];                          \
            p[j] = fmaf(E * mm, rpo, eb);                                     \
        }                                                                     \
        uint2v wv2;                                                           \
        wv2[0] = cvtpk(p[0], p[1]);                                           \
        wv2[1] = cvtpk(p[2], p[3]);                                           \
        *(f32x4*)(srow + (c) * 64 + sub * 16 + 4 * lg) = ov;                  \
        *(uint2v*)&wl[wid][lr][sub * 16 + 4 * lg] = wv2;                      \
    }                                                                         \
} while (0)

#define PVTILE(c) do {                                                        \
    __builtin_amdgcn_s_setprio(1);                                            \
    _Pragma("unroll")                                                         \
    for (int ks = 0; ks < 64; ks += 32) {                                     \
        short8 af = *(const short8*)&wl[wid][lr][ks + 8 * lg];                \
        _Pragma("unroll")                                                     \
        for (int dt = 0; dt < 4; ++dt) {                                      \
            const u16* vb = SH + 8192 + ((c) & 1) * 4096 + (dt * 16 + lr) * 64; \
            short8 vf = *(const short8*)(vb + (ks ? (kswz ^ 32) : kswz));     \
            apv[dt] = mfma16(af, vf, apv[dt]);                                \
        }                                                                     \
    }                                                                         \
    __builtin_amdgcn_s_setprio(0);                                            \
} while (0)

// 512 blocks x 8 waves (128 q-rows/block), single tranche, XCD-swizzled.
// LB(512,2): VGPR cap 128 (caps 84/64 spill). R14 schedule: stage-before-wait
// dbuf + counted vmcnt (load-issue earliness dominates barrier count; fused
// passes beat any split; this is the measured optimum of the session).
__global__ __launch_bounds__(512, 2) void attn_kernel(
    const u16* __restrict__ Qw, const u16* __restrict__ Kw, const u16* __restrict__ Vt,
    const float* __restrict__ policy, u16* __restrict__ outpre, float* __restrict__ softout) {
    __shared__ u16 SH[16384];      // p1: 2x16KB K128 dbuf; p2: K dbuf | V dbuf
    __shared__ u16 wl[8][16][72];
    __shared__ float maskL[N_];

    const int t = threadIdx.x;
    const int wid = t >> 6, l = t & 63, lg = (l >> 4), lr = l & 15;
    const int srow_ = t >> 3, sch_ = (t & 7) ^ ((t >> 3) & 7);
    const int kswz = (lg ^ (lr & 7)) * 8;

    const int bid = blockIdx.x;              // 512 = 8 xcd * 64
    const int xcd = bid & 7, rr = bid >> 3;
    const int g = rr >> 3, rt = rr & 7;
    const int bh = g * 8 + xcd;
    const int b = bh >> 3, h = bh & 7;
    const int n0 = rt * 128 + wid * 16;
    const int q = n0 + lr;

    const u16* Qb = Qw + ((size_t)bh * N_ + n0) * DH_;
    const u16* Kb = Kw + (size_t)bh * N_ * DH_;
    const u16* Vb = Vt + (size_t)bh * DH_ * N_;
    const float* pol = policy + b * N_;

    short8 qf0 = *(const short8*)(Qb + lr * DH_ + 8 * lg);
    short8 qf1 = *(const short8*)(Qb + lr * DH_ + 32 + 8 * lg);

    {
        float2 pv = *(const float2*)(pol + t * 2);
        maskL[t * 2 + 0] = pv.x > 0.5f ? 1.f : 0.f;
        maskL[t * 2 + 1] = pv.y > 0.5f ? 1.f : 0.f;
    }
    __syncthreads();

    // ---- pass 1: row sums, 128-col staged K phases ----
    float sp = 0.f, so = 0.f;
    STAGE_K2(0);
#define ITER1(c2, n) do { STAGE_K2(n); WAITB(2); SUM128(c2); ENDB; } while (0)
    ITER1(0, 1); ITER1(1, 2); ITER1(2, 3); ITER1(3, 4);
    ITER1(4, 5); ITER1(5, 6); ITER1(6, 7);
    WAITB(0); SUM128(7); ENDB;

    sp += __shfl_xor(sp, 16); sp += __shfl_xor(sp, 32);
    so += __shfl_xor(so, 16); so += __shfl_xor(so, 32);
    const float rip = 1.f / sp;
    const float rpo = 1.f / (so + EPS_);
    const float eb = EPSN_ * rpo;

    // ---- pass 2: softmax stream + PV, staged K+V ----
    f32x4 apv[4];
#pragma unroll
    for (int i = 0; i < 4; i++) apv[i] = (f32x4){0, 0, 0, 0};
    float* srow = softout + ((size_t)bh * N_ + q) * N_;

    STAGE_K(0); STAGE_V(0);
    // c=0: outstanding S0(2)+S1(2) -> wait S0 => vmcnt(2)
    STAGE_K(1); STAGE_V(1); WAITB(2); QKTILE(0); PVTILE(0); ENDB;
    // c=1..14: younger-than-S(c) = stores(4)+S(c+1)(2) => vmcnt(6)
#define ITER2(c, n) do { STAGE_K(n); STAGE_V(n); WAITB(6); QKTILE(c); PVTILE(c); ENDB; } while (0)
    ITER2(1, 2);  ITER2(2, 3);  ITER2(3, 4);  ITER2(4, 5);
    ITER2(5, 6);  ITER2(6, 7);  ITER2(7, 8);  ITER2(8, 9);
    ITER2(9, 10); ITER2(10, 11); ITER2(11, 12); ITER2(12, 13);
    ITER2(13, 14); ITER2(14, 15);
    // c=15: younger-than-S15 = stores_c14(4) => vmcnt(4)
    WAITB(4); QKTILE(15); PVTILE(15);

#pragma unroll
    for (int dt = 0; dt < 4; dt++) {
#pragma unroll
        for (int j = 0; j < 4; j++) {
            outpre[(size_t)(b * N_ + n0 + 4 * lg + j) * DIM_ + h * DH_ + dt * 16 + lr]
                = f2b(apv[dt][j]);
        }
    }
}

extern "C" void kernel_launch(void* const* d_in, const int* in_sizes, int n_in,
                              void* d_out, int out_size, void* d_ws, size_t ws_size,
                              hipStream_t stream) {
    const float* x      = (const float*)d_in[0];
    const float* policy = (const float*)d_in[1];
    const float* W_qkv  = (const float*)d_in[2];
    const float* W_out  = (const float*)d_in[3];
    const float* b_out  = (const float*)d_in[4];
    float* out = (float*)d_out;
    float* softout = out + (size_t)B_ * N_ * DIM_;

    // ws: wqkvT 1.5M | woutT .5M | Xb 8M | Qw 8M | Kw 8M | Vt 8M | pre 8M
    char* ws = (char*)d_ws;
    u16* wqkvT = (u16*)ws;
    u16* woutT = (u16*)(ws + 1572864);
    u16* Xb    = (u16*)(ws + 2097152);
    u16* Qw    = (u16*)(ws + 10485760);
    u16* Kw    = (u16*)(ws + 18874368);
    u16* Vt    = (u16*)(ws + 27262976);
    u16* pre   = (u16*)(ws + 35651584);

    prep<<<2304, 256, 0, stream>>>(W_qkv, W_out, x, wqkvT, woutT, Xb);
    gemm_qkv<<<dim3(12, 64), 256, 0, stream>>>(Xb, wqkvT, Qw, Kw, Vt);
    attn_kernel<<<512, 512, 0, stream>>>(Qw, Kw, Vt, policy, pre, softout);
    gemm_out<<<dim3(4, 64), 256, 0, stream>>>(pre, woutT, b_out, out);
}